// Round 1
// baseline (201.794 us; speedup 1.0000x reference)
//
#include <hip/hip_runtime.h>

typedef __attribute__((ext_vector_type(8))) short bf16x8;
typedef __attribute__((ext_vector_type(4))) float f32x4;

__device__ __forceinline__ unsigned short f2bf(float f) {
    unsigned int u = __float_as_uint(f);
    u += 0x7fffu + ((u >> 16) & 1u);
    return (unsigned short)(u >> 16);
}

// ---------------------------------------------------------------------------
// Kernel 1: QKV projection.  out[m,n] = sum_k x[m,k] * W[n,k] + b[n]
// M=8192 (B*S), K=1024, N=128 per weight.  grid = (64 m-tiles, 3 weights)
// Writes: Q bf16 [8192][128] (pre-scaled by 1/sqrt(128)), K bf16 [8192][128],
//         Vt bf16 [4][128][2048] (transposed for PV B-operand frags)
// ---------------------------------------------------------------------------
__global__ __launch_bounds__(256) void qkv_gemm(
    const float* __restrict__ x,
    const float* __restrict__ Wq, const float* __restrict__ bq,
    const float* __restrict__ Wk, const float* __restrict__ bk,
    const float* __restrict__ Wv, const float* __restrict__ bv,
    unsigned short* __restrict__ Qg,
    unsigned short* __restrict__ Kg,
    unsigned short* __restrict__ Vtg)
{
    constexpr int LDA = 72;  // 64 + 8 pad: 144B row = 16B-aligned, bank stride 36 dw
    __shared__ unsigned short As[128][LDA];
    __shared__ unsigned short Bs[128][LDA];

    const int tid  = threadIdx.x;
    const int lane = tid & 63;
    const int wid  = tid >> 6;
    const int quad = lane >> 4;
    const int ln   = lane & 15;
    const int wm   = wid >> 1, wn = wid & 1;

    const int mbase = blockIdx.x * 128;
    const int nb    = blockIdx.y;  // 0=Q 1=K 2=V
    const float* Wsel = (nb == 0) ? Wq : ((nb == 1) ? Wk : Wv);
    const float* bsel = (nb == 0) ? bq : ((nb == 1) ? bk : bv);

    const int srow = tid >> 1;          // 0..127
    const int scol = (tid & 1) * 32;    // 0 or 32

    f32x4 acc[4][4];
#pragma unroll
    for (int mt = 0; mt < 4; mt++)
#pragma unroll
        for (int nt = 0; nt < 4; nt++) acc[mt][nt] = (f32x4){0.f, 0.f, 0.f, 0.f};

    for (int kb = 0; kb < 16; kb++) {
        __syncthreads();
        const float* xs = x    + (size_t)(mbase + srow) * 1024 + kb * 64 + scol;
        const float* ws = Wsel + (size_t)srow * 1024 + kb * 64 + scol;
#pragma unroll
        for (int i = 0; i < 8; i++) {
            float4 fx = ((const float4*)xs)[i];
            float4 fw = ((const float4*)ws)[i];
            ushort4 ux = { f2bf(fx.x), f2bf(fx.y), f2bf(fx.z), f2bf(fx.w) };
            ushort4 uw = { f2bf(fw.x), f2bf(fw.y), f2bf(fw.z), f2bf(fw.w) };
            *(ushort4*)&As[srow][scol + i * 4] = ux;
            *(ushort4*)&Bs[srow][scol + i * 4] = uw;
        }
        __syncthreads();
#pragma unroll
        for (int ks = 0; ks < 2; ks++) {
            bf16x8 a[4], b[4];
#pragma unroll
            for (int t = 0; t < 4; t++) {
                a[t] = *(const bf16x8*)&As[wm * 64 + t * 16 + ln][ks * 32 + quad * 8];
                b[t] = *(const bf16x8*)&Bs[wn * 64 + t * 16 + ln][ks * 32 + quad * 8];
            }
#pragma unroll
            for (int mt = 0; mt < 4; mt++)
#pragma unroll
                for (int nt = 0; nt < 4; nt++)
                    acc[mt][nt] = __builtin_amdgcn_mfma_f32_16x16x32_bf16(
                        a[mt], b[nt], acc[mt][nt], 0, 0, 0);
        }
    }

    // epilogue: bias, (scale for Q), convert, store
    const float scale = (nb == 0) ? 0.08838834764831845f : 1.0f;  // 1/sqrt(128)
    float bias_v[4];
#pragma unroll
    for (int nt = 0; nt < 4; nt++) bias_v[nt] = bsel[wn * 64 + nt * 16 + ln];

    if (nb < 2) {
        unsigned short* dst = (nb == 0) ? Qg : Kg;
#pragma unroll
        for (int mt = 0; mt < 4; mt++)
#pragma unroll
            for (int nt = 0; nt < 4; nt++)
#pragma unroll
                for (int r = 0; r < 4; r++) {
                    int m = mbase + wm * 64 + mt * 16 + quad * 4 + r;
                    int d = wn * 64 + nt * 16 + ln;
                    dst[(size_t)m * 128 + d] =
                        f2bf((acc[mt][nt][r] + bias_v[nt]) * scale);
                }
    } else {
        const int bb = mbase >> 11;      // batch
        const int sb = mbase & 2047;     // s within batch
#pragma unroll
        for (int mt = 0; mt < 4; mt++)
#pragma unroll
            for (int nt = 0; nt < 4; nt++) {
                int dd = wn * 64 + nt * 16 + ln;
                int s0 = sb + wm * 64 + mt * 16 + quad * 4;
                ushort4 u = { f2bf(acc[mt][nt][0] + bias_v[nt]),
                              f2bf(acc[mt][nt][1] + bias_v[nt]),
                              f2bf(acc[mt][nt][2] + bias_v[nt]),
                              f2bf(acc[mt][nt][3] + bias_v[nt]) };
                *(ushort4*)&Vtg[((size_t)bb * 128 + dd) * 2048 + s0] = u;
            }
    }
}

// ---------------------------------------------------------------------------
// Kernel 2: causal flash attention.  grid = 4 batches * 32 q-tiles (descending
// qtile order so heavy blocks schedule first).  BQ=64, BK=64, 4 waves,
// each wave owns 16 q-rows.  Q pre-scaled, so S = Q@K^T directly.
// ---------------------------------------------------------------------------
__global__ __launch_bounds__(256) void flash_attn(
    const unsigned short* __restrict__ Qg,
    const unsigned short* __restrict__ Kg,
    const unsigned short* __restrict__ Vtg,
    float* __restrict__ out)
{
    constexpr int LQ = 136, LV = 72, LP = 72;
    __shared__ unsigned short Qs[64][LQ];
    __shared__ unsigned short Ks[64][LQ];
    __shared__ unsigned short Vts[128][LV];
    __shared__ unsigned short Pl[64][LP];

    const int b     = blockIdx.x >> 5;
    const int qtile = 31 - (blockIdx.x & 31);
    const int q0    = qtile * 64;
    const int tid   = threadIdx.x;
    const int lane  = tid & 63, w = tid >> 6, quad = lane >> 4, ln = lane & 15;

    // load Q tile (64 x 128 bf16) once
    {
        int c = (tid & 15) * 8;
#pragma unroll
        for (int i = 0; i < 4; i++) {
            int row = (tid >> 4) + i * 16;
            *(uint4*)&Qs[row][c] =
                *(const uint4*)&Qg[((size_t)b * 2048 + q0 + row) * 128 + c];
        }
    }

    float m_i[4], l_i[4];
    f32x4 Ofr[8];
#pragma unroll
    for (int r = 0; r < 4; r++) { m_i[r] = -__builtin_inff(); l_i[r] = 0.f; }
#pragma unroll
    for (int dt = 0; dt < 8; dt++) Ofr[dt] = (f32x4){0.f, 0.f, 0.f, 0.f};

    for (int kt = 0; kt <= qtile; kt++) {
        __syncthreads();
        {
            int c = (tid & 15) * 8;
#pragma unroll
            for (int i = 0; i < 4; i++) {
                int row = (tid >> 4) + i * 16;
                *(uint4*)&Ks[row][c] =
                    *(const uint4*)&Kg[((size_t)b * 2048 + kt * 64 + row) * 128 + c];
            }
            int c2 = (tid & 7) * 8;
#pragma unroll
            for (int i = 0; i < 4; i++) {
                int dd = (tid >> 3) + i * 32;
                *(uint4*)&Vts[dd][c2] =
                    *(const uint4*)&Vtg[((size_t)b * 128 + dd) * 2048 + kt * 64 + c2];
            }
        }
        __syncthreads();

        // S = Q @ K^T  (wave's 16 q-rows x 64 keys)
        bf16x8 qa[4];
#pragma unroll
        for (int ks = 0; ks < 4; ks++)
            qa[ks] = *(const bf16x8*)&Qs[w * 16 + ln][ks * 32 + quad * 8];
        f32x4 sfr[4];
#pragma unroll
        for (int ct = 0; ct < 4; ct++) {
            f32x4 s = (f32x4){0.f, 0.f, 0.f, 0.f};
#pragma unroll
            for (int ks = 0; ks < 4; ks++) {
                bf16x8 kf = *(const bf16x8*)&Ks[ct * 16 + ln][ks * 32 + quad * 8];
                s = __builtin_amdgcn_mfma_f32_16x16x32_bf16(qa[ks], kf, s, 0, 0, 0);
            }
            sfr[ct] = s;
        }

        // causal mask (only the diagonal tile needs it)
        if (kt == qtile) {
#pragma unroll
            for (int ct = 0; ct < 4; ct++)
#pragma unroll
                for (int r = 0; r < 4; r++)
                    if (ct * 16 + ln > w * 16 + quad * 4 + r)
                        sfr[ct][r] = -__builtin_inff();
        }

        // online softmax (per q-row; row lives across 16 lanes of one quad)
        float mrow[4];
#pragma unroll
        for (int r = 0; r < 4; r++) mrow[r] = -__builtin_inff();
#pragma unroll
        for (int ct = 0; ct < 4; ct++)
#pragma unroll
            for (int r = 0; r < 4; r++) mrow[r] = fmaxf(mrow[r], sfr[ct][r]);
#pragma unroll
        for (int off = 1; off < 16; off <<= 1)
#pragma unroll
            for (int r = 0; r < 4; r++)
                mrow[r] = fmaxf(mrow[r], __shfl_xor(mrow[r], off, 64));

        float alpha[4], rs[4];
#pragma unroll
        for (int r = 0; r < 4; r++) {
            float mn = fmaxf(m_i[r], mrow[r]);
            alpha[r] = __expf(m_i[r] - mn);
            m_i[r]   = mn;
            rs[r]    = 0.f;
        }
#pragma unroll
        for (int ct = 0; ct < 4; ct++)
#pragma unroll
            for (int r = 0; r < 4; r++) {
                float p = __expf(sfr[ct][r] - m_i[r]);
                rs[r] += p;
                Pl[w * 16 + quad * 4 + r][ct * 16 + ln] = f2bf(p);
            }
#pragma unroll
        for (int off = 1; off < 16; off <<= 1)
#pragma unroll
            for (int r = 0; r < 4; r++) rs[r] += __shfl_xor(rs[r], off, 64);
#pragma unroll
        for (int r = 0; r < 4; r++) l_i[r] = l_i[r] * alpha[r] + rs[r];
#pragma unroll
        for (int dt = 0; dt < 8; dt++)
#pragma unroll
            for (int r = 0; r < 4; r++) Ofr[dt][r] *= alpha[r];

        __syncthreads();  // Pl write->read ordering (and uniform barrier)

        // O += P @ V   (P via LDS round-trip into A-operand layout)
#pragma unroll
        for (int kstep = 0; kstep < 2; kstep++) {
            bf16x8 pa = *(const bf16x8*)&Pl[w * 16 + ln][kstep * 32 + quad * 8];
#pragma unroll
            for (int dt = 0; dt < 8; dt++) {
                bf16x8 vf = *(const bf16x8*)&Vts[dt * 16 + ln][kstep * 32 + quad * 8];
                Ofr[dt] = __builtin_amdgcn_mfma_f32_16x16x32_bf16(pa, vf, Ofr[dt], 0, 0, 0);
            }
        }
    }

    // epilogue: normalize and store fp32
    float inv[4];
#pragma unroll
    for (int r = 0; r < 4; r++) inv[r] = 1.0f / l_i[r];
#pragma unroll
    for (int dt = 0; dt < 8; dt++)
#pragma unroll
        for (int r = 0; r < 4; r++) {
            size_t q = (size_t)b * 2048 + q0 + w * 16 + quad * 4 + r;
            out[q * 128 + dt * 16 + ln] = Ofr[dt][r] * inv[r];
        }
}

extern "C" void kernel_launch(void* const* d_in, const int* in_sizes, int n_in,
                              void* d_out, int out_size, void* d_ws, size_t ws_size,
                              hipStream_t stream) {
    const float* x  = (const float*)d_in[0];
    const float* Wq = (const float*)d_in[1];
    const float* bq = (const float*)d_in[2];
    const float* Wk = (const float*)d_in[3];
    const float* bk = (const float*)d_in[4];
    const float* Wv = (const float*)d_in[5];
    const float* bv = (const float*)d_in[6];
    float* out = (float*)d_out;

    unsigned short* ws  = (unsigned short*)d_ws;
    unsigned short* Qg  = ws;                            // 8192*128 bf16 = 2MB
    unsigned short* Kg  = ws + (size_t)8192 * 128;       // 2MB
    unsigned short* Vtg = ws + (size_t)2 * 8192 * 128;   // [4][128][2048] 2MB

    dim3 g1(64, 3);
    qkv_gemm<<<g1, 256, 0, stream>>>(x, Wq, bq, Wk, bk, Wv, bv, Qg, Kg, Vtg);
    flash_attn<<<128, 256, 0, stream>>>(Qg, Kg, Vtg, out);
}

// Round 2
// 145.162 us; speedup vs baseline: 1.3901x; 1.3901x over previous
//
#include <hip/hip_runtime.h>

typedef __attribute__((ext_vector_type(8))) short bf16x8;
typedef __attribute__((ext_vector_type(4))) float f32x4;

__device__ __forceinline__ unsigned short f2bf(float f) {
    unsigned int u = __float_as_uint(f);
    u += 0x7fffu + ((u >> 16) & 1u);
    return (unsigned short)(u >> 16);
}
__device__ __forceinline__ unsigned int pack2bf(float lo, float hi) {
    return (unsigned int)f2bf(lo) | ((unsigned int)f2bf(hi) << 16);
}
__device__ __forceinline__ void async_ld16(void* lds, const void* g) {
    __builtin_amdgcn_global_load_lds(
        (const __attribute__((address_space(1))) unsigned int*)g,
        (__attribute__((address_space(3))) unsigned int*)lds, 16, 0, 0);
}

// ---------------------------------------------------------------------------
// Kernel 0: convert x[8192x1024] f32 -> bf16, and Wq/Wk/Wv -> Wcat[384x1024] bf16
// ---------------------------------------------------------------------------
__global__ __launch_bounds__(256) void convert_bf16(
    const float* __restrict__ x,
    const float* __restrict__ Wq, const float* __restrict__ Wk,
    const float* __restrict__ Wv,
    unsigned short* __restrict__ xbf, unsigned short* __restrict__ Wcat)
{
    const size_t XN8 = (size_t)8192 * 1024 / 8;   // 1048576
    const size_t TN8 = XN8 + (size_t)3 * 128 * 1024 / 8;
    size_t i = (size_t)blockIdx.x * blockDim.x + threadIdx.x;
    const size_t stride = (size_t)gridDim.x * blockDim.x;
    for (; i < TN8; i += stride) {
        const float* src;
        unsigned short* dst;
        if (i < XN8) {
            src = x + i * 8;
            dst = xbf + i * 8;
        } else {
            size_t o = (i - XN8) * 8;
            int sel = (int)(o >> 17);  // 131072 elems per W
            const float* W = (sel == 0) ? Wq : ((sel == 1) ? Wk : Wv);
            src = W + (o & 131071);
            dst = Wcat + o;
        }
        float4 f0 = ((const float4*)src)[0];
        float4 f1 = ((const float4*)src)[1];
        uint4 u;
        u.x = pack2bf(f0.x, f0.y); u.y = pack2bf(f0.z, f0.w);
        u.z = pack2bf(f1.x, f1.y); u.w = pack2bf(f1.z, f1.w);
        *(uint4*)dst = u;
    }
}

// ---------------------------------------------------------------------------
// Kernel 1: QKV GEMM (bf16 in, bf16 out).  C[m,n] = xbf[m,:] . Wcat[n,:] + b
// M=8192, K=1024, N=384 (3 x 128).  Tile 64(M) x 128(N), BK=64.
// grid = 384 flat blocks: m = bid/3, nb = bid%3.  global_load_lds staging.
// ---------------------------------------------------------------------------
__global__ __launch_bounds__(256) void qkv_gemm(
    const unsigned short* __restrict__ xbf,
    const unsigned short* __restrict__ Wcat,
    const float* __restrict__ bq, const float* __restrict__ bk,
    const float* __restrict__ bv,
    unsigned short* __restrict__ Qg,
    unsigned short* __restrict__ Kg,
    unsigned short* __restrict__ Vtg)
{
    __shared__ unsigned short As[64 * 64];    // [row][k] contiguous
    __shared__ unsigned short Bs[128 * 64];

    const int tid  = threadIdx.x;
    const int lane = tid & 63;
    const int w    = tid >> 6;
    const int quad = lane >> 4;
    const int ln   = lane & 15;
    const int wm   = w >> 1, wn = w & 1;       // wave tile: 32(M) x 64(N)
    const int lr   = lane >> 3;                 // staging row-in-chunk
    const int lc   = (lane & 7) * 8;            // staging col elems

    const int bid   = blockIdx.x;
    const int mbase = (bid / 3) * 64;
    const int nb    = bid % 3;                  // 0=Q 1=K 2=V
    const unsigned short* Wsel = Wcat + (size_t)nb * 128 * 1024;

    f32x4 acc[2][4];
#pragma unroll
    for (int mt = 0; mt < 2; mt++)
#pragma unroll
        for (int nt = 0; nt < 4; nt++) acc[mt][nt] = (f32x4){0.f, 0.f, 0.f, 0.f};

    for (int kb = 0; kb < 16; kb++) {
        __syncthreads();
        const int kcol = kb * 64 + lc;
        // A: 64x64 = 8 chunks of 8 rows; wave w stages chunks w*2, w*2+1
#pragma unroll
        for (int j = 0; j < 2; j++) {
            int chunk = w * 2 + j;
            int row = chunk * 8 + lr;
            async_ld16(&As[chunk * 512 + lane * 8],
                       xbf + (size_t)(mbase + row) * 1024 + kcol);
        }
        // B: 128x64 = 16 chunks; wave w stages chunks w*4 .. w*4+3
#pragma unroll
        for (int j = 0; j < 4; j++) {
            int chunk = w * 4 + j;
            int row = chunk * 8 + lr;
            async_ld16(&Bs[chunk * 512 + lane * 8],
                       Wsel + (size_t)row * 1024 + kcol);
        }
        __syncthreads();
#pragma unroll
        for (int ks = 0; ks < 2; ks++) {
            bf16x8 a[2], b[4];
#pragma unroll
            for (int mt = 0; mt < 2; mt++)
                a[mt] = *(const bf16x8*)&As[(wm * 32 + mt * 16 + ln) * 64 + ks * 32 + quad * 8];
#pragma unroll
            for (int nt = 0; nt < 4; nt++)
                b[nt] = *(const bf16x8*)&Bs[(wn * 64 + nt * 16 + ln) * 64 + ks * 32 + quad * 8];
#pragma unroll
            for (int mt = 0; mt < 2; mt++)
#pragma unroll
                for (int nt = 0; nt < 4; nt++)
                    acc[mt][nt] = __builtin_amdgcn_mfma_f32_16x16x32_bf16(
                        a[mt], b[nt], acc[mt][nt], 0, 0, 0);
        }
    }

    const float scale = (nb == 0) ? 0.08838834764831845f : 1.0f;  // 1/sqrt(128)
    const float* bsel = (nb == 0) ? bq : ((nb == 1) ? bk : bv);
    float bias_v[4];
#pragma unroll
    for (int nt = 0; nt < 4; nt++) bias_v[nt] = bsel[wn * 64 + nt * 16 + ln];

    if (nb < 2) {
        unsigned short* dst = (nb == 0) ? Qg : Kg;
#pragma unroll
        for (int mt = 0; mt < 2; mt++)
#pragma unroll
            for (int nt = 0; nt < 4; nt++)
#pragma unroll
                for (int r = 0; r < 4; r++) {
                    int m = mbase + wm * 32 + mt * 16 + quad * 4 + r;
                    int d = wn * 64 + nt * 16 + ln;
                    dst[(size_t)m * 128 + d] =
                        f2bf((acc[mt][nt][r] + bias_v[nt]) * scale);
                }
    } else {
#pragma unroll
        for (int mt = 0; mt < 2; mt++)
#pragma unroll
            for (int nt = 0; nt < 4; nt++) {
                int dd = wn * 64 + nt * 16 + ln;
                int m0 = mbase + wm * 32 + mt * 16 + quad * 4;
                int bb = m0 >> 11, s0 = m0 & 2047;
                ushort4 u = { f2bf(acc[mt][nt][0] + bias_v[nt]),
                              f2bf(acc[mt][nt][1] + bias_v[nt]),
                              f2bf(acc[mt][nt][2] + bias_v[nt]),
                              f2bf(acc[mt][nt][3] + bias_v[nt]) };
                *(ushort4*)&Vtg[((size_t)bb * 128 + dd) * 2048 + s0] = u;
            }
    }
}

// ---------------------------------------------------------------------------
// Kernel 2: causal flash attention with KV-split.
// grid = (4 b, 32 qtile, 8 chunk); chunk c covers kt in [4c, min(4c+4, q+1));
// active iff c <= q/4.  Writes unnormalized O (bf16) + per-row (m,l) partials.
// ---------------------------------------------------------------------------
__global__ __launch_bounds__(256) void flash_attn(
    const unsigned short* __restrict__ Qg,
    const unsigned short* __restrict__ Kg,
    const unsigned short* __restrict__ Vtg,
    unsigned short* __restrict__ Opart,
    float2* __restrict__ ml)
{
    constexpr int LQ = 136, LV = 72, LP = 72;
    __shared__ unsigned short Qs[64][LQ];
    __shared__ unsigned short Ks[64][LQ];
    __shared__ unsigned short Vts[128][LV];
    __shared__ unsigned short Pl[64][LP];

    const int b = blockIdx.x;
    const int q = blockIdx.y;
    const int c = blockIdx.z;
    if (c > (q >> 2)) return;

    const int m4 = q >> 2, r4 = q & 3;
    const int pidx = b * 144 + q + 2 * m4 * (m4 - 1) + r4 * m4 + c;
    const int k0 = c * 4;
    const int kend = (c * 4 + 4 < q + 1) ? (c * 4 + 4) : (q + 1);

    const int q0   = q * 64;
    const int tid  = threadIdx.x;
    const int lane = tid & 63, w = tid >> 6, quad = lane >> 4, ln = lane & 15;

    // load Q tile (64 x 128 bf16)
    {
        int col = (tid & 15) * 8;
#pragma unroll
        for (int i = 0; i < 4; i++) {
            int row = (tid >> 4) + i * 16;
            *(uint4*)&Qs[row][col] =
                *(const uint4*)&Qg[((size_t)b * 2048 + q0 + row) * 128 + col];
        }
    }

    float m_i[4], l_i[4];
    f32x4 Ofr[8];
#pragma unroll
    for (int r = 0; r < 4; r++) { m_i[r] = -__builtin_inff(); l_i[r] = 0.f; }
#pragma unroll
    for (int dt = 0; dt < 8; dt++) Ofr[dt] = (f32x4){0.f, 0.f, 0.f, 0.f};

    for (int kt = k0; kt < kend; kt++) {
        __syncthreads();
        {
            int col = (tid & 15) * 8;
#pragma unroll
            for (int i = 0; i < 4; i++) {
                int row = (tid >> 4) + i * 16;
                *(uint4*)&Ks[row][col] =
                    *(const uint4*)&Kg[((size_t)b * 2048 + kt * 64 + row) * 128 + col];
            }
            int c2 = (tid & 7) * 8;
#pragma unroll
            for (int i = 0; i < 4; i++) {
                int dd = (tid >> 3) + i * 32;
                *(uint4*)&Vts[dd][c2] =
                    *(const uint4*)&Vtg[((size_t)b * 128 + dd) * 2048 + kt * 64 + c2];
            }
        }
        __syncthreads();

        // S = Q @ K^T
        bf16x8 qa[4];
#pragma unroll
        for (int ks = 0; ks < 4; ks++)
            qa[ks] = *(const bf16x8*)&Qs[w * 16 + ln][ks * 32 + quad * 8];
        f32x4 sfr[4];
#pragma unroll
        for (int ct = 0; ct < 4; ct++) {
            f32x4 s = (f32x4){0.f, 0.f, 0.f, 0.f};
#pragma unroll
            for (int ks = 0; ks < 4; ks++) {
                bf16x8 kf = *(const bf16x8*)&Ks[ct * 16 + ln][ks * 32 + quad * 8];
                s = __builtin_amdgcn_mfma_f32_16x16x32_bf16(qa[ks], kf, s, 0, 0, 0);
            }
            sfr[ct] = s;
        }

        if (kt == q) {  // diagonal tile: causal mask
#pragma unroll
            for (int ct = 0; ct < 4; ct++)
#pragma unroll
                for (int r = 0; r < 4; r++)
                    if (ct * 16 + ln > w * 16 + quad * 4 + r)
                        sfr[ct][r] = -__builtin_inff();
        }

        // online softmax
        float mrow[4];
#pragma unroll
        for (int r = 0; r < 4; r++) mrow[r] = -__builtin_inff();
#pragma unroll
        for (int ct = 0; ct < 4; ct++)
#pragma unroll
            for (int r = 0; r < 4; r++) mrow[r] = fmaxf(mrow[r], sfr[ct][r]);
#pragma unroll
        for (int off = 1; off < 16; off <<= 1)
#pragma unroll
            for (int r = 0; r < 4; r++)
                mrow[r] = fmaxf(mrow[r], __shfl_xor(mrow[r], off, 64));

        float alpha[4], rs[4];
#pragma unroll
        for (int r = 0; r < 4; r++) {
            float mn = fmaxf(m_i[r], mrow[r]);
            alpha[r] = __expf(m_i[r] - mn);
            m_i[r]   = mn;
            rs[r]    = 0.f;
        }
#pragma unroll
        for (int ct = 0; ct < 4; ct++)
#pragma unroll
            for (int r = 0; r < 4; r++) {
                float p = __expf(sfr[ct][r] - m_i[r]);
                rs[r] += p;
                Pl[w * 16 + quad * 4 + r][ct * 16 + ln] = f2bf(p);
            }
#pragma unroll
        for (int off = 1; off < 16; off <<= 1)
#pragma unroll
            for (int r = 0; r < 4; r++) rs[r] += __shfl_xor(rs[r], off, 64);
#pragma unroll
        for (int r = 0; r < 4; r++) l_i[r] = l_i[r] * alpha[r] + rs[r];
#pragma unroll
        for (int dt = 0; dt < 8; dt++)
#pragma unroll
            for (int r = 0; r < 4; r++) Ofr[dt][r] *= alpha[r];

        __syncthreads();

        // O += P @ V
#pragma unroll
        for (int kstep = 0; kstep < 2; kstep++) {
            bf16x8 pa = *(const bf16x8*)&Pl[w * 16 + ln][kstep * 32 + quad * 8];
#pragma unroll
            for (int dt = 0; dt < 8; dt++) {
                bf16x8 vf = *(const bf16x8*)&Vts[dt * 16 + ln][kstep * 32 + quad * 8];
                Ofr[dt] = __builtin_amdgcn_mfma_f32_16x16x32_bf16(pa, vf, Ofr[dt], 0, 0, 0);
            }
        }
    }

    // epilogue: write unnormalized partials
#pragma unroll
    for (int dt = 0; dt < 8; dt++)
#pragma unroll
        for (int r = 0; r < 4; r++) {
            int row = w * 16 + quad * 4 + r;
            Opart[((size_t)pidx * 64 + row) * 128 + dt * 16 + ln] = f2bf(Ofr[dt][r]);
        }
    if (ln == 0) {
#pragma unroll
        for (int r = 0; r < 4; r++) {
            int row = w * 16 + quad * 4 + r;
            ml[(size_t)pidx * 64 + row] = make_float2(m_i[r], l_i[r]);
        }
    }
}

// ---------------------------------------------------------------------------
// Kernel 3: combine partials.  grid = 128 (b*32+q), 256 threads.
// ---------------------------------------------------------------------------
__global__ __launch_bounds__(256) void combine(
    const unsigned short* __restrict__ Opart,
    const float2* __restrict__ ml,
    float* __restrict__ out)
{
    const int b = blockIdx.x >> 5, q = blockIdx.x & 31;
    const int m4 = q >> 2, r4 = q & 3;
    const int pbase = b * 144 + q + 2 * m4 * (m4 - 1) + r4 * m4;
    const int nc = m4 + 1;

    const int row = threadIdx.x >> 2;
    const int cg  = (threadIdx.x & 3) * 32;

    float mc[8], lc[8], wgt[8];
    float mmax = -__builtin_inff();
    for (int c = 0; c < nc; c++) {
        float2 t = ml[(size_t)(pbase + c) * 64 + row];
        mc[c] = t.x; lc[c] = t.y;
        mmax = fmaxf(mmax, t.x);
    }
    float lsum = 0.f;
    for (int c = 0; c < nc; c++) {
        wgt[c] = __expf(mc[c] - mmax);
        lsum += lc[c] * wgt[c];
    }
    const float inv = 1.0f / lsum;

    for (int v = 0; v < 4; v++) {
        int col = cg + v * 8;
        float acc[8];
#pragma unroll
        for (int k = 0; k < 8; k++) acc[k] = 0.f;
        for (int c = 0; c < nc; c++) {
            uint4 u = *(const uint4*)&Opart[((size_t)(pbase + c) * 64 + row) * 128 + col];
            float f0 = __uint_as_float(u.x << 16);
            float f1 = __uint_as_float(u.x & 0xffff0000u);
            float f2 = __uint_as_float(u.y << 16);
            float f3 = __uint_as_float(u.y & 0xffff0000u);
            float f4 = __uint_as_float(u.z << 16);
            float f5 = __uint_as_float(u.z & 0xffff0000u);
            float f6 = __uint_as_float(u.w << 16);
            float f7 = __uint_as_float(u.w & 0xffff0000u);
            float wc = wgt[c];
            acc[0] += wc * f0; acc[1] += wc * f1; acc[2] += wc * f2; acc[3] += wc * f3;
            acc[4] += wc * f4; acc[5] += wc * f5; acc[6] += wc * f6; acc[7] += wc * f7;
        }
        float* o = &out[((size_t)b * 2048 + q * 64 + row) * 128 + col];
        float4 o0 = { acc[0] * inv, acc[1] * inv, acc[2] * inv, acc[3] * inv };
        float4 o1 = { acc[4] * inv, acc[5] * inv, acc[6] * inv, acc[7] * inv };
        ((float4*)o)[0] = o0;
        ((float4*)o)[1] = o1;
    }
}

extern "C" void kernel_launch(void* const* d_in, const int* in_sizes, int n_in,
                              void* d_out, int out_size, void* d_ws, size_t ws_size,
                              hipStream_t stream) {
    const float* x  = (const float*)d_in[0];
    const float* Wq = (const float*)d_in[1];
    const float* bq = (const float*)d_in[2];
    const float* Wk = (const float*)d_in[3];
    const float* bk = (const float*)d_in[4];
    const float* Wv = (const float*)d_in[5];
    const float* bv = (const float*)d_in[6];
    float* out = (float*)d_out;

    // Workspace layout (bytes):
    //  region A [0, 17563648): phase 1-2: xbf (16 MB) + Wcat (768 KB)
    //                          phase 3-4: Opart (9 MB) + ml (288 KB)  (aliased)
    //  region B [17563648, ..): Qg (2 MB) + Kg (2 MB) + Vtg (2 MB)
    char* wsb = (char*)d_ws;
    unsigned short* xbf  = (unsigned short*)wsb;                       // 16777216 B
    unsigned short* Wcat = (unsigned short*)(wsb + 16777216);          // 786432 B
    unsigned short* Opart = (unsigned short*)wsb;                      // 9437184 B
    float2*         ml   = (float2*)(wsb + 9437184);                   // 294912 B
    unsigned short* Qg   = (unsigned short*)(wsb + 17563648);
    unsigned short* Kg   = Qg + (size_t)8192 * 128;
    unsigned short* Vtg  = Qg + (size_t)2 * 8192 * 128;

    convert_bf16<<<1024, 256, 0, stream>>>(x, Wq, Wk, Wv, xbf, Wcat);
    qkv_gemm<<<384, 256, 0, stream>>>(xbf, Wcat, bq, bk, bv, Qg, Kg, Vtg);
    flash_attn<<<dim3(4, 32, 8), 256, 0, stream>>>(Qg, Kg, Vtg, Opart, ml);
    combine<<<128, 256, 0, stream>>>(Opart, ml, out);
}